// Round 10
// baseline (610.428 us; speedup 1.0000x reference)
//
#include <hip/hip_runtime.h>
#include <hip/hip_bf16.h>
#include <stdint.h>

typedef unsigned short u16;
typedef __attribute__((ext_vector_type(8))) short short8;
typedef __attribute__((ext_vector_type(4))) float f32x4;

// ---------- helpers ----------
__device__ __forceinline__ uint32_t f2bf(float f) {
    union { float f; uint32_t u; } c; c.f = f;
    uint32_t u = c.u;
    u += 0x7fffu + ((u >> 16) & 1u);   // round-to-nearest-even
    return u >> 16;
}

__device__ __forceinline__ void glds16(const void* g, void* l) {
    __builtin_amdgcn_global_load_lds(
        (const __attribute__((address_space(1))) uint32_t*)g,
        (__attribute__((address_space(3))) uint32_t*)l,
        16, 0, 0);
}

__device__ __forceinline__ uint2 wrow2(float4 wi, float4 pp, float4 gv) {
    uint32_t lo = f2bf(wi.x + pp.x * gv.x) | (f2bf(wi.y + pp.y * gv.y) << 16);
    uint32_t hi = f2bf(wi.z + pp.z * gv.z) | (f2bf(wi.w + pp.w * gv.w) << 16);
    return make_uint2(lo, hi);
}

// ---------- kernel 1: g_p = FWHT_1024(D_p[:1024] * V) / 1024, for 4 params ----------
__global__ void fwht_g_kernel(const float* __restrict__ V,
                              const float* __restrict__ D0, const float* __restrict__ D1,
                              const float* __restrict__ D2, const float* __restrict__ D3,
                              float* __restrict__ g) {
    __shared__ float s[1024];
    int t = threadIdx.x;
    const float* D = (blockIdx.x == 0) ? D0 : (blockIdx.x == 1) ? D1 :
                     (blockIdx.x == 2) ? D2 : D3;
    s[t] = D[t] * V[t];
    __syncthreads();
    #pragma unroll
    for (int st = 512; st >= 1; st >>= 1) {
        float a = s[t];
        float b = s[t ^ st];
        __syncthreads();
        s[t] = (t & st) ? (b - a) : (a + b);
        __syncthreads();
    }
    g[blockIdx.x * 1024 + t] = s[t] * (1.0f / 1024.0f);
}

// ---------- kernel 2: bias = init + PP * g[i&1023] ----------
__global__ void bias_kernel(const float* __restrict__ init, const float* __restrict__ PP,
                            const float* __restrict__ g, float* __restrict__ out, int n) {
    int i = blockIdx.x * blockDim.x + threadIdx.x;
    if (i < n) out[i] = init[i] + PP[i] * g[i & 1023];
}

// ---------- kernel 3: f32 -> bf16 cast (x), 4 elems/thread ----------
__global__ void cast_kernel(const float* __restrict__ in, u16* __restrict__ out, int n4) {
    int i = blockIdx.x * blockDim.x + threadIdx.x;
    if (i >= n4) return;
    float4 v = ((const float4*)in)[i];
    uint32_t lo = f2bf(v.x) | (f2bf(v.y) << 16);
    uint32_t hi = f2bf(v.z) | (f2bf(v.w) << 16);
    ((uint2*)out)[i] = make_uint2(lo, hi);
}

// ---------- kernel 4: fused W-gen + split-K GEMM, v7 (producer/consumer waves) ----------
// 512 thr = 8 waves. Waves 0-3: consumers (MFMA on buf c, issue A-glds for buf c^1).
// Waves 4-7: producers (depth-2 W prefetch in named regs, cvt+swizzled ds_write of
// B(s+1) into buf c^1). ONE s_barrier per K-step; producers wait lgkmcnt(0) only so
// their W(s+2) loads stay in flight across the barrier; consumers wait vmcnt(0) for
// their own glds (covered by their MFMA phase).
// BM=256, BN=64, BK=64, double-buffered LDS (80 KB) -> 2 WG/CU; grid 512 WGs.
__global__ __launch_bounds__(512, 4) void gemm_fused(const u16* __restrict__ A,
                                                     const float* __restrict__ Winit,
                                                     const float* __restrict__ PP,
                                                     const float* __restrict__ gvec,
                                                     float* __restrict__ P,
                                                     int M, int N, int K, int Kslice) {
    constexpr int BM = 256, BN = 64, BK = 64;
    __shared__ u16 As[2][BM * BK];   // 2 x 32 KB
    __shared__ u16 Bs[2][BN * BK];   // 2 x 8 KB

    const int t    = threadIdx.x;
    const int wid  = t >> 6;
    const int lane = t & 63;
    const bool consumer = (wid < 4);

    const int bn = blockIdx.x, bm = blockIdx.y, sk = blockIdx.z;
    const int k_beg = sk * Kslice;
    const int kmax  = k_beg + Kslice - BK;
    const int npair = (Kslice / BK) / 2;      // 8
    const int nstep = Kslice / BK;            // 16

    // ---- consumer mapping ----
    const int ct = t & 255;          // consumer-local tid (valid when wid<4)
    const int fr = lane & 15;
    const int fq = lane >> 4;
    const int rx = (fr & 7) << 4;    // read-side swizzle xor (bytes)
    const u16* Abase = A + (size_t)(bm * BM) * K;

    // ---- producer mapping (valid when wid>=4) ----
    const int pt  = t - 256;
    const int rB  = pt >> 4;         // 0..15
    const int cB  = (pt & 15) * 4;   // f32 col
    const int cb8 = (pt & 15) * 8;   // byte col
    const int wxor = (rB & 7) << 4;  // write-side swizzle xor
    const float* Wb = Winit + (size_t)(bn * BN + rB) * K;
    const float* Pb = PP    + (size_t)(bn * BN + rB) * K;
    const size_t rstride = (size_t)16 * K;

    float4 w00, w01, w02, w03, p00, p01, p02, p03;   // W set0 (even steps)
    float4 w10, w11, w12, w13, p10, p11, p12, p13;   // W set1 (odd steps)

#define PF_W0(k0) do {                                        \
        const float* wp_ = Wb + (k0) + cB;                    \
        const float* qp_ = Pb + (k0) + cB;                    \
        w00 = *(const float4*)(wp_);                          \
        w01 = *(const float4*)(wp_ + rstride);                \
        w02 = *(const float4*)(wp_ + 2 * rstride);            \
        w03 = *(const float4*)(wp_ + 3 * rstride);            \
        p00 = *(const float4*)(qp_);                          \
        p01 = *(const float4*)(qp_ + rstride);                \
        p02 = *(const float4*)(qp_ + 2 * rstride);            \
        p03 = *(const float4*)(qp_ + 3 * rstride);            \
    } while (0)

#define PF_W1(k0) do {                                        \
        const float* wp_ = Wb + (k0) + cB;                    \
        const float* qp_ = Pb + (k0) + cB;                    \
        w10 = *(const float4*)(wp_);                          \
        w11 = *(const float4*)(wp_ + rstride);                \
        w12 = *(const float4*)(wp_ + 2 * rstride);            \
        w13 = *(const float4*)(wp_ + 3 * rstride);            \
        p10 = *(const float4*)(qp_);                          \
        p11 = *(const float4*)(qp_ + rstride);                \
        p12 = *(const float4*)(qp_ + 2 * rstride);            \
        p13 = *(const float4*)(qp_ + 3 * rstride);            \
    } while (0)

#define WRITE_B0(k0, buf) do {                                                      \
        float4 gv_ = *(const float4*)(gvec + (((k0) + cB) & 1023));                 \
        char* Bp_ = (char*)Bs[buf];                                                 \
        *(uint2*)(Bp_ + ((((rB +  0) * 128 + cb8)) ^ wxor)) = wrow2(w00, p00, gv_); \
        *(uint2*)(Bp_ + ((((rB + 16) * 128 + cb8)) ^ wxor)) = wrow2(w01, p01, gv_); \
        *(uint2*)(Bp_ + ((((rB + 32) * 128 + cb8)) ^ wxor)) = wrow2(w02, p02, gv_); \
        *(uint2*)(Bp_ + ((((rB + 48) * 128 + cb8)) ^ wxor)) = wrow2(w03, p03, gv_); \
    } while (0)

#define WRITE_B1(k0, buf) do {                                                      \
        float4 gv_ = *(const float4*)(gvec + (((k0) + cB) & 1023));                 \
        char* Bp_ = (char*)Bs[buf];                                                 \
        *(uint2*)(Bp_ + ((((rB +  0) * 128 + cb8)) ^ wxor)) = wrow2(w10, p10, gv_); \
        *(uint2*)(Bp_ + ((((rB + 16) * 128 + cb8)) ^ wxor)) = wrow2(w11, p11, gv_); \
        *(uint2*)(Bp_ + ((((rB + 32) * 128 + cb8)) ^ wxor)) = wrow2(w12, p12, gv_); \
        *(uint2*)(Bp_ + ((((rB + 48) * 128 + cb8)) ^ wxor)) = wrow2(w13, p13, gv_); \
    } while (0)

// A staging by consumers: 256x64 tile = 2048 chunks of 16B; 8 per consumer thread.
// LDS dest linear (glds), global SOURCE col-group pre-swizzled.
#define STAGE_A(k0, buf) do {                                                       \
        _Pragma("unroll")                                                           \
        for (int q_ = 0; q_ < 8; ++q_) {                                            \
            int L_ = q_ * 256 + ct;                                                 \
            int row_ = L_ >> 3;                                                     \
            int cg_ = (L_ & 7) ^ (row_ & 7);                                        \
            glds16(Abase + (size_t)row_ * K + (k0) + cg_ * 8, As[buf] + L_ * 8);    \
        }                                                                           \
    } while (0)

// consumer MFMA: wave wid owns rows wid*64..+64; full BN=64; acc[4][4].
#define MFMA_STEP(buf) do {                                                         \
        const char* Ap_ = (const char*)As[buf];                                     \
        const char* Bp_ = (const char*)Bs[buf];                                     \
        __builtin_amdgcn_s_setprio(1);                                              \
        _Pragma("unroll")                                                           \
        for (int ks_ = 0; ks_ < 2; ++ks_) {                                         \
            const int co_ = (ks_ * 64 + fq * 16) ^ rx;                              \
            short8 a_[4], b_[4];                                                    \
            _Pragma("unroll")                                                       \
            for (int m_ = 0; m_ < 4; ++m_)                                          \
                a_[m_] = *(const short8*)(Ap_ +                                     \
                          (wid * 64 + m_ * 16 + fr) * 128 + co_);                   \
            _Pragma("unroll")                                                       \
            for (int n_ = 0; n_ < 4; ++n_)                                          \
                b_[n_] = *(const short8*)(Bp_ + (n_ * 16 + fr) * 128 + co_);        \
            _Pragma("unroll")                                                       \
            for (int m_ = 0; m_ < 4; ++m_)                                          \
                _Pragma("unroll")                                                   \
                for (int n_ = 0; n_ < 4; ++n_)                                      \
                    acc[m_][n_] = __builtin_amdgcn_mfma_f32_16x16x32_bf16(          \
                        a_[m_], b_[n_], acc[m_][n_], 0, 0, 0);                      \
        }                                                                           \
        __builtin_amdgcn_s_setprio(0);                                              \
    } while (0)

    f32x4 acc[4][4];
    #pragma unroll
    for (int m = 0; m < 4; ++m)
        #pragma unroll
        for (int n = 0; n < 4; ++n)
            acc[m][n] = (f32x4){0.f, 0.f, 0.f, 0.f};

    // ---- prologue: buf0 = step 0 ----
    if (consumer) {
        STAGE_A(k_beg, 0);
        asm volatile("s_waitcnt vmcnt(0)" ::: "memory");
    } else {
        PF_W0(k_beg);                  // W(0) -> set0
        PF_W1(k_beg + BK);             // W(1) -> set1 (stays in flight)
        WRITE_B0(k_beg, 0);            // B(0): auto-waits set0 (vmcnt(8))
        asm volatile("s_waitcnt lgkmcnt(0)" ::: "memory");
    }
    __builtin_amdgcn_s_barrier();
    __builtin_amdgcn_sched_barrier(0);

    // ---- main loop: pairs of K-steps, 1 barrier/step ----
    int kk = k_beg;
    #pragma unroll 1
    for (int p = 0; p < npair; ++p, kk += 2 * BK) {
        const int s0 = 2 * p;
        int n2 = kk + 2 * BK; if (n2 > kmax) n2 = kmax;   // clamp (dummy at tail)
        int n3 = kk + 3 * BK; if (n3 > kmax) n3 = kmax;

        // even step s0: compute buf0; prep s0+1 into buf1
        if (consumer) {
            STAGE_A(kk + BK, 1);                          // A(s0+1) (s0+1<=15 always)
            __builtin_amdgcn_sched_barrier(0);
            MFMA_STEP(0);
            asm volatile("s_waitcnt vmcnt(0)" ::: "memory");
        } else {
            PF_W0(n2);                                    // W(s0+2) -> set0
            __builtin_amdgcn_sched_barrier(0);
            WRITE_B1(kk + BK, 1);                         // B(s0+1) from set1 (old)
            asm volatile("s_waitcnt lgkmcnt(0)" ::: "memory");
        }
        __builtin_amdgcn_s_barrier();
        __builtin_amdgcn_sched_barrier(0);

        // odd step s1 = s0+1: compute buf1; prep s0+2 into buf0
        if (consumer) {
            if (s0 + 2 < nstep) STAGE_A(kk + 2 * BK, 0);  // A(s0+2)
            __builtin_amdgcn_sched_barrier(0);
            MFMA_STEP(1);
            asm volatile("s_waitcnt vmcnt(0)" ::: "memory");
        } else {
            if (s0 + 2 < nstep) {
                PF_W1(n3);                                // W(s0+3) -> set1
                __builtin_amdgcn_sched_barrier(0);
                WRITE_B0(kk + 2 * BK, 0);                 // B(s0+2) from set0
            }
            asm volatile("s_waitcnt lgkmcnt(0)" ::: "memory");
        }
        __builtin_amdgcn_s_barrier();
        __builtin_amdgcn_sched_barrier(0);
    }

#undef PF_W0
#undef PF_W1
#undef WRITE_B0
#undef WRITE_B1
#undef STAGE_A
#undef MFMA_STEP

    // epilogue: consumers write f32 partial tile
    if (consumer) {
        float* Pp = P + (size_t)sk * M * N;
        #pragma unroll
        for (int m = 0; m < 4; ++m) {
            int grow0 = bm * BM + wid * 64 + m * 16 + fq * 4;
            #pragma unroll
            for (int n = 0; n < 4; ++n) {
                int gcol = bn * BN + n * 16 + fr;
                #pragma unroll
                for (int j = 0; j < 4; ++j)
                    Pp[(size_t)(grow0 + j) * N + gcol] = acc[m][n][j];
            }
        }
    }
}

// ---------- kernel 5: reduce S partials + bias (+relu) -> bf16 or f32 ----------
template <typename OutT, bool RELU, int S>
__global__ void reduce_kernel(const float* __restrict__ P, const float* __restrict__ bias,
                              OutT* __restrict__ out, int MN, int N) {
    int i = blockIdx.x * blockDim.x + threadIdx.x;   // handles 4 elems
    if (i * 4 >= MN) return;
    int e = i * 4;
    int col = e & (N - 1);
    float4 acc = ((const float4*)(P + e))[0];
    #pragma unroll
    for (int s = 1; s < S; ++s) {
        float4 p = ((const float4*)(P + (size_t)s * MN + e))[0];
        acc.x += p.x; acc.y += p.y; acc.z += p.z; acc.w += p.w;
    }
    float4 bv = *((const float4*)(bias + col));
    acc.x += bv.x; acc.y += bv.y; acc.z += bv.z; acc.w += bv.w;
    if (RELU) {
        acc.x = fmaxf(acc.x, 0.f); acc.y = fmaxf(acc.y, 0.f);
        acc.z = fmaxf(acc.z, 0.f); acc.w = fmaxf(acc.w, 0.f);
    }
    if constexpr (sizeof(OutT) == 2) {
        uint32_t lo = f2bf(acc.x) | (f2bf(acc.y) << 16);
        uint32_t hi = f2bf(acc.z) | (f2bf(acc.w) << 16);
        ((uint2*)out)[i] = make_uint2(lo, hi);
    } else {
        ((float4*)out)[i] = acc;
    }
}

// ---------- launch ----------
extern "C" void kernel_launch(void* const* d_in, const int* in_sizes, int n_in,
                              void* d_out, int out_size, void* d_ws, size_t ws_size,
                              hipStream_t stream) {
    (void)in_sizes; (void)n_in; (void)out_size; (void)ws_size;

    const float* x       = (const float*)d_in[0];
    const float* V       = (const float*)d_in[1];
    const float* W1_init = (const float*)d_in[2];
    const float* D_W1    = (const float*)d_in[3];
    const float* PP_W1   = (const float*)d_in[4];
    const float* b1_init = (const float*)d_in[5];
    const float* D_b1    = (const float*)d_in[6];
    const float* PP_b1   = (const float*)d_in[7];
    const float* W2_init = (const float*)d_in[8];
    const float* D_W2    = (const float*)d_in[9];
    const float* PP_W2   = (const float*)d_in[10];
    const float* b2_init = (const float*)d_in[11];
    const float* D_b2    = (const float*)d_in[12];
    const float* PP_b2   = (const float*)d_in[13];

    constexpr size_t MB = 1024 * 1024;
    char* ws = (char*)d_ws;
    float* g    = (float*)(ws);                      // 4x1024 f32: [W1 | b1 | W2 | b2]
    float* b1w  = (float*)(ws + 16384);              // 4096 f32
    float* b2w  = (float*)(ws + 32768);              // 4096 f32
    u16*   xb   = (u16*)(ws + 65536);                // 512x4096 bf16 (4 MB)
    u16*   hb   = (u16*)(ws + 65536 + 4 * MB);       // 512x4096 bf16 (4 MB)
    float* Pbuf = (float*)(ws + 65536 + 8 * MB);     // 4x512x4096 f32 (32 MB)

    const int M = 512, N = 4096, K = 4096, S = 4, Kslice = K / S;

    fwht_g_kernel<<<4, 1024, 0, stream>>>(V, D_W1, D_b1, D_W2, D_b2, g);
    bias_kernel<<<4, 1024, 0, stream>>>(b1_init, PP_b1, g + 1024, b1w, 4096);
    bias_kernel<<<4, 1024, 0, stream>>>(b2_init, PP_b2, g + 3072, b2w, 4096);
    cast_kernel<<<2048, 256, 0, stream>>>(x, xb, M * K / 4);

    // layer 1: fused W1-gen GEMM (grid 64 x 2 x 4 = 512 WGs of 8 waves)
    gemm_fused<<<dim3(N / 64, M / 256, S), 512, 0, stream>>>(xb, W1_init, PP_W1, g, Pbuf, M, N, K, Kslice);
    reduce_kernel<u16, true, S><<<M * N / 4 / 256, 256, 0, stream>>>(Pbuf, b1w, hb, M * N, N);

    // layer 2: fused W2-gen GEMM
    gemm_fused<<<dim3(N / 64, M / 256, S), 512, 0, stream>>>(hb, W2_init, PP_W2, g + 2048, Pbuf, M, N, K, Kslice);
    reduce_kernel<float, false, S><<<M * N / 4 / 256, 256, 0, stream>>>(Pbuf, b2w, (float*)d_out, M * N, N);
}

// Round 11
// 133.947 us; speedup vs baseline: 4.5572x; 4.5572x over previous
//
#include <hip/hip_runtime.h>
#include <hip/hip_bf16.h>
#include <stdint.h>

typedef unsigned short u16;
typedef __attribute__((ext_vector_type(8))) short short8;
typedef __attribute__((ext_vector_type(4))) float f32x4;

// ---------- helpers ----------
__device__ __forceinline__ uint32_t f2bf(float f) {
    union { float f; uint32_t u; } c; c.f = f;
    uint32_t u = c.u;
    u += 0x7fffu + ((u >> 16) & 1u);   // round-to-nearest-even
    return u >> 16;
}

__device__ __forceinline__ void glds16(const void* g, void* l) {
    __builtin_amdgcn_global_load_lds(
        (const __attribute__((address_space(1))) uint32_t*)g,
        (__attribute__((address_space(3))) uint32_t*)l,
        16, 0, 0);
}

// ---------- kernel 1: g_p = FWHT_1024(D_p[:1024] * V) / 1024, for 4 params ----------
__global__ void fwht_g_kernel(const float* __restrict__ V,
                              const float* __restrict__ D0, const float* __restrict__ D1,
                              const float* __restrict__ D2, const float* __restrict__ D3,
                              float* __restrict__ g) {
    __shared__ float s[1024];
    int t = threadIdx.x;
    const float* D = (blockIdx.x == 0) ? D0 : (blockIdx.x == 1) ? D1 :
                     (blockIdx.x == 2) ? D2 : D3;
    s[t] = D[t] * V[t];
    __syncthreads();
    #pragma unroll
    for (int st = 512; st >= 1; st >>= 1) {
        float a = s[t];
        float b = s[t ^ st];
        __syncthreads();
        s[t] = (t & st) ? (b - a) : (a + b);
        __syncthreads();
    }
    g[blockIdx.x * 1024 + t] = s[t] * (1.0f / 1024.0f);
}

// ---------- kernel 2: bias = init + PP * g[i&1023] ----------
__global__ void bias_kernel(const float* __restrict__ init, const float* __restrict__ PP,
                            const float* __restrict__ g, float* __restrict__ out, int n) {
    int i = blockIdx.x * blockDim.x + threadIdx.x;
    if (i < n) out[i] = init[i] + PP[i] * g[i & 1023];
}

// ---------- kernel 3: f32 -> bf16 cast (x), 4 elems/thread ----------
__global__ void cast_kernel(const float* __restrict__ in, u16* __restrict__ out, int n4) {
    int i = blockIdx.x * blockDim.x + threadIdx.x;
    if (i >= n4) return;
    float4 v = ((const float4*)in)[i];
    uint32_t lo = f2bf(v.x) | (f2bf(v.y) << 16);
    uint32_t hi = f2bf(v.z) | (f2bf(v.w) << 16);
    ((uint2*)out)[i] = make_uint2(lo, hi);
}

// ---------- kernel 4: W_bf16 = bf16(W_init + PP * g[idx&1023]), 4 elems/thread ----------
__global__ void wmat_kernel(const float* __restrict__ init, const float* __restrict__ PP,
                            const float* __restrict__ g, u16* __restrict__ out, int n4) {
    int i = blockIdx.x * blockDim.x + threadIdx.x;
    if (i >= n4) return;
    int e = i * 4;
    float4 wi = ((const float4*)init)[i];
    float4 pp = ((const float4*)PP)[i];
    float4 gv = *((const float4*)(g + (e & 1023)));
    uint32_t lo = f2bf(wi.x + pp.x * gv.x) | (f2bf(wi.y + pp.y * gv.y) << 16);
    uint32_t hi = f2bf(wi.z + pp.z * gv.z) | (f2bf(wi.w + pp.w * gv.w) << 16);
    ((uint2*)out)[i] = make_uint2(lo, hi);
}

// ---------- kernel 5: split-K GEMM partial: P[s] = A(MxKs) @ B^T(NxKs) ----------
// Non-fused (A, B both bf16). BM=128, BN=64, BK=64, single-buffered LDS 24 KB.
// Grid (N/64, M/128, S) = 1024 WGs -> 4 WG/CU (the TLP fix for the 2-barrier
// structure; m114 implicit overlap hides the barrier drain at >=3 WG/CU).
// XOR swizzle both tiles (validated: BANK_CONFLICT -> 0).
// 4 waves 2x2: wave tile 64x32, acc[4][2].
__global__ __launch_bounds__(256, 4) void gemm_splitk(const u16* __restrict__ A,
                                                      const u16* __restrict__ B,
                                                      float* __restrict__ P,
                                                      int M, int N, int K, int Kslice) {
    constexpr int BM = 128, BN = 64, BK = 64;
    __shared__ u16 As[BM * BK];   // 16 KB
    __shared__ u16 Bs[BN * BK];   // 8 KB

    const int t    = threadIdx.x;
    const int wid  = t >> 6;
    const int lane = t & 63;
    const int wr   = wid >> 1;        // 0..1: 64-row block of A
    const int wc   = wid & 1;         // 0..1: 32-col block of B
    const int fr   = lane & 15;
    const int fq   = lane >> 4;
    const int rx   = (fr & 7) << 4;   // read-side swizzle xor (bytes)

    const int bn = blockIdx.x, bm = blockIdx.y, sk = blockIdx.z;
    const int k_beg = sk * Kslice;

    const u16* Abase = A + (size_t)(bm * BM) * K;
    const u16* Bbase = B + (size_t)(bn * BN) * K;

    f32x4 acc[4][2];
    #pragma unroll
    for (int m = 0; m < 4; ++m)
        #pragma unroll
        for (int n = 0; n < 2; ++n)
            acc[m][n] = (f32x4){0.f, 0.f, 0.f, 0.f};

    #pragma unroll 1
    for (int k0 = k_beg; k0 < k_beg + Kslice; k0 += BK) {
        // stage A: 128x64 = 1024 16B-chunks = 4 rounds; source col pre-swizzled
        #pragma unroll
        for (int q = 0; q < 4; ++q) {
            int L = q * 256 + t;
            int row = L >> 3;
            int cg  = (L & 7) ^ (row & 7);
            glds16(Abase + (size_t)row * K + k0 + cg * 8, As + L * 8);
        }
        // stage B: 64x64 = 512 chunks = 2 rounds
        #pragma unroll
        for (int q = 0; q < 2; ++q) {
            int L = q * 256 + t;
            int row = L >> 3;
            int cg  = (L & 7) ^ (row & 7);
            glds16(Bbase + (size_t)row * K + k0 + cg * 8, Bs + L * 8);
        }
        __syncthreads();

        const char* Ap = (const char*)As;
        const char* Bp = (const char*)Bs;
        __builtin_amdgcn_s_setprio(1);
        #pragma unroll
        for (int ks = 0; ks < 2; ++ks) {
            const int co = (ks * 64 + fq * 16) ^ rx;
            short8 a[4], b[2];
            #pragma unroll
            for (int m = 0; m < 4; ++m)
                a[m] = *(const short8*)(Ap + (wr * 64 + m * 16 + fr) * 128 + co);
            #pragma unroll
            for (int n = 0; n < 2; ++n)
                b[n] = *(const short8*)(Bp + (wc * 32 + n * 16 + fr) * 128 + co);
            #pragma unroll
            for (int m = 0; m < 4; ++m)
                #pragma unroll
                for (int n = 0; n < 2; ++n)
                    acc[m][n] = __builtin_amdgcn_mfma_f32_16x16x32_bf16(a[m], b[n], acc[m][n], 0, 0, 0);
        }
        __builtin_amdgcn_s_setprio(0);
        __syncthreads();
    }

    // epilogue: write f32 partial tile
    float* Pp = P + (size_t)sk * M * N;
    #pragma unroll
    for (int m = 0; m < 4; ++m) {
        int grow0 = bm * BM + wr * 64 + m * 16 + fq * 4;
        #pragma unroll
        for (int n = 0; n < 2; ++n) {
            int gcol = bn * BN + wc * 32 + n * 16 + fr;
            #pragma unroll
            for (int j = 0; j < 4; ++j)
                Pp[(size_t)(grow0 + j) * N + gcol] = acc[m][n][j];
        }
    }
}

// ---------- kernel 6: reduce S partials + bias (+relu) -> bf16 or f32 ----------
template <typename OutT, bool RELU, int S>
__global__ void reduce_kernel(const float* __restrict__ P, const float* __restrict__ bias,
                              OutT* __restrict__ out, int MN, int N) {
    int i = blockIdx.x * blockDim.x + threadIdx.x;   // handles 4 elems
    if (i * 4 >= MN) return;
    int e = i * 4;
    int col = e & (N - 1);
    float4 acc = ((const float4*)(P + e))[0];
    #pragma unroll
    for (int s = 1; s < S; ++s) {
        float4 p = ((const float4*)(P + (size_t)s * MN + e))[0];
        acc.x += p.x; acc.y += p.y; acc.z += p.z; acc.w += p.w;
    }
    float4 bv = *((const float4*)(bias + col));
    acc.x += bv.x; acc.y += bv.y; acc.z += bv.z; acc.w += bv.w;
    if (RELU) {
        acc.x = fmaxf(acc.x, 0.f); acc.y = fmaxf(acc.y, 0.f);
        acc.z = fmaxf(acc.z, 0.f); acc.w = fmaxf(acc.w, 0.f);
    }
    if constexpr (sizeof(OutT) == 2) {
        uint32_t lo = f2bf(acc.x) | (f2bf(acc.y) << 16);
        uint32_t hi = f2bf(acc.z) | (f2bf(acc.w) << 16);
        ((uint2*)out)[i] = make_uint2(lo, hi);
    } else {
        ((float4*)out)[i] = acc;
    }
}

// ---------- launch ----------
extern "C" void kernel_launch(void* const* d_in, const int* in_sizes, int n_in,
                              void* d_out, int out_size, void* d_ws, size_t ws_size,
                              hipStream_t stream) {
    (void)in_sizes; (void)n_in; (void)out_size; (void)ws_size;

    const float* x       = (const float*)d_in[0];
    const float* V       = (const float*)d_in[1];
    const float* W1_init = (const float*)d_in[2];
    const float* D_W1    = (const float*)d_in[3];
    const float* PP_W1   = (const float*)d_in[4];
    const float* b1_init = (const float*)d_in[5];
    const float* D_b1    = (const float*)d_in[6];
    const float* PP_b1   = (const float*)d_in[7];
    const float* W2_init = (const float*)d_in[8];
    const float* D_W2    = (const float*)d_in[9];
    const float* PP_W2   = (const float*)d_in[10];
    const float* b2_init = (const float*)d_in[11];
    const float* D_b2    = (const float*)d_in[12];
    const float* PP_b2   = (const float*)d_in[13];

    constexpr size_t MB = 1024 * 1024;
    char* ws = (char*)d_ws;
    float* g    = (float*)(ws);                      // 4x1024 f32: [W1 | b1 | W2 | b2]
    float* b1w  = (float*)(ws + 16384);              // 4096 f32
    float* b2w  = (float*)(ws + 32768);              // 4096 f32
    u16*   xb   = (u16*)(ws + 65536);                // 512x4096 bf16 (4 MB)
    u16*   hb   = (u16*)(ws + 65536 + 4 * MB);       // 512x4096 bf16 (4 MB)
    u16*   wbuf = (u16*)(ws + 65536 + 8 * MB);       // 4096x4096 bf16 (32 MB), W1 then W2
    float* Pbuf = (float*)(ws + 65536 + 40 * MB);    // 4x512x4096 f32 (32 MB)

    const int M = 512, N = 4096, K = 4096, S = 4, Kslice = K / S;

    fwht_g_kernel<<<4, 1024, 0, stream>>>(V, D_W1, D_b1, D_W2, D_b2, g);
    bias_kernel<<<4, 1024, 0, stream>>>(b1_init, PP_b1, g + 1024, b1w, 4096);
    bias_kernel<<<4, 1024, 0, stream>>>(b2_init, PP_b2, g + 3072, b2w, 4096);
    cast_kernel<<<2048, 256, 0, stream>>>(x, xb, M * K / 4);

    // layer 1: materialize W1 (BW-bound, ~25 us), then GEMM at 4 WG/CU
    wmat_kernel<<<16384, 256, 0, stream>>>(W1_init, PP_W1, g, wbuf, 4096 * 4096 / 4);
    gemm_splitk<<<dim3(N / 64, M / 128, S), 256, 0, stream>>>(xb, wbuf, Pbuf, M, N, K, Kslice);
    reduce_kernel<u16, true, S><<<M * N / 4 / 256, 256, 0, stream>>>(Pbuf, b1w, hb, M * N, N);

    // layer 2 (wbuf reused for W2; Pbuf reused)
    wmat_kernel<<<16384, 256, 0, stream>>>(W2_init, PP_W2, g + 2048, wbuf, 4096 * 4096 / 4);
    gemm_splitk<<<dim3(N / 64, M / 128, S), 256, 0, stream>>>(hb, wbuf, Pbuf, M, N, K, Kslice);
    reduce_kernel<float, false, S><<<M * N / 4 / 256, 256, 0, stream>>>(Pbuf, b2w, (float*)d_out, M * N, N);
}